// Round 10
// baseline (921.932 us; speedup 1.0000x reference)
//
#include <hip/hip_runtime.h>
#include <hip/hip_bf16.h>
#include <math.h>

// Problem constants (fixed by the reference)
#define GN 100000   // nodes
#define GE 1200000  // edges
#define GB 128      // graphs
#define GF 92       // raw features
#define GD 64       // hidden dim
#define GL 3        // CGConv layers
#define GZ 129      // 2*D+1

#define HS 65       // padded LDS h-tile stride (2-way bank alias = free)

// round-to-nearest-even fp32 -> bf16 (returned in low 16 bits)
__device__ __forceinline__ unsigned int f2bf_rne(float x)
{
    unsigned int u = __float_as_uint(x);
    u += 0x7fffu + ((u >> 16) & 1u);
    return u >> 16;
}

// ---------------------------------------------------------------------------
// Fused pre-MLP (3 layers) + P0 + Q0.  (R14 form -- measured best: ~150us.)
// 4-way column split (wave = 16-col slice), R=2 nodes/thread, weights + h
// tile staged in LDS. NOTE: premlp chains h through its own writes, so the
// scalar-pipe trick (pjq below) is NOT K$-safe here -- keep LDS form.
// ---------------------------------------------------------------------------
__global__ __launch_bounds__(256, 2) void premlp_kernel(
    const float* __restrict__ X,
    const float* __restrict__ W0, const float* __restrict__ b0,
    const float* __restrict__ W1, const float* __restrict__ b1,
    const float* __restrict__ W2, const float* __restrict__ b2,
    const float* __restrict__ WfD, const float* __restrict__ WsD,   // rows 0..63
    const float* __restrict__ WfS, const float* __restrict__ WsS,   // rows 64..127
    const float* __restrict__ bf, const float* __restrict__ bs,
    float* __restrict__ hout, unsigned int* __restrict__ Pout,
    float* __restrict__ Qout, int N)
{
    __shared__ __align__(16) float Wl[5888];    // 23 KB weight stage (W0 needs it all)
    __shared__ float hl[128 * HS];              // 33.3 KB padded h tile (128 nodes)
    const int tid = threadIdx.x;
    const int lane = tid & 63;
    const int col0 = (tid >> 6) * 16;           // this wave's column slice
    const int base = blockIdx.x * 128;
    const int n0 = base + lane;
    const int n1 = base + 64 + lane;
    const int nn0 = (n0 < N) ? n0 : (N - 1);
    const int nn1 = (n1 < N) ? n1 : (N - 1);
    const bool act0 = (n0 < N), act1 = (n1 < N);

    float a0[16], a1[16], s0[16], s1[16];

    // ---- stage W0 (92x64 = 1472 float4) ----
    {
        const float4* __restrict__ s4 = (const float4*)W0;
        float4* __restrict__ d4 = (float4*)Wl;
        for (int i = tid; i < 1472; i += 256) d4[i] = s4[i];
    }
    __syncthreads();

    // ---- layer 0: K=92 ----
#pragma unroll
    for (int j = 0; j < 16; ++j) { a0[j] = b0[col0 + j]; a1[j] = a0[j]; }
    {
        const float4* __restrict__ r40 = (const float4*)(X + (size_t)nn0 * GF);
        const float4* __restrict__ r41 = (const float4*)(X + (size_t)nn1 * GF);
        for (int c = 0; c < 23; ++c) {
            float4 v0 = r40[c];
            float4 v1 = r41[c];
            const float* __restrict__ w = Wl + c * 256 + col0;
#pragma unroll
            for (int j = 0; j < 16; ++j) {
                float wa = w[j], wb = w[64 + j], wc = w[128 + j], wd = w[192 + j];
                a0[j] = fmaf(v0.x, wa, a0[j]);
                a0[j] = fmaf(v0.y, wb, a0[j]);
                a0[j] = fmaf(v0.z, wc, a0[j]);
                a0[j] = fmaf(v0.w, wd, a0[j]);
                a1[j] = fmaf(v1.x, wa, a1[j]);
                a1[j] = fmaf(v1.y, wb, a1[j]);
                a1[j] = fmaf(v1.z, wc, a1[j]);
                a1[j] = fmaf(v1.w, wd, a1[j]);
            }
        }
    }
    __syncthreads();    // all Wl reads done
#pragma unroll
    for (int j = 0; j < 16; ++j) {
        hl[lane * HS + col0 + j] = fmaxf(a0[j], 0.f);
        hl[(64 + lane) * HS + col0 + j] = fmaxf(a1[j], 0.f);
    }
    {
        const float4* __restrict__ s4 = (const float4*)W1;
        float4* __restrict__ d4 = (float4*)Wl;
        for (int i = tid; i < 1024; i += 256) d4[i] = s4[i];
    }
    __syncthreads();

    // ---- layer 1 ----
#pragma unroll
    for (int j = 0; j < 16; ++j) { a0[j] = b1[col0 + j]; a1[j] = a0[j]; }
    for (int c = 0; c < 16; ++c) {
        float h0 = hl[lane * HS + 4 * c + 0];
        float h1 = hl[lane * HS + 4 * c + 1];
        float h2 = hl[lane * HS + 4 * c + 2];
        float h3 = hl[lane * HS + 4 * c + 3];
        float g0 = hl[(64 + lane) * HS + 4 * c + 0];
        float g1 = hl[(64 + lane) * HS + 4 * c + 1];
        float g2 = hl[(64 + lane) * HS + 4 * c + 2];
        float g3 = hl[(64 + lane) * HS + 4 * c + 3];
        const float* __restrict__ w = Wl + c * 256 + col0;
#pragma unroll
        for (int j = 0; j < 16; ++j) {
            float wa = w[j], wb = w[64 + j], wc = w[128 + j], wd = w[192 + j];
            a0[j] = fmaf(h0, wa, a0[j]);
            a0[j] = fmaf(h1, wb, a0[j]);
            a0[j] = fmaf(h2, wc, a0[j]);
            a0[j] = fmaf(h3, wd, a0[j]);
            a1[j] = fmaf(g0, wa, a1[j]);
            a1[j] = fmaf(g1, wb, a1[j]);
            a1[j] = fmaf(g2, wc, a1[j]);
            a1[j] = fmaf(g3, wd, a1[j]);
        }
    }
    __syncthreads();
#pragma unroll
    for (int j = 0; j < 16; ++j) {
        hl[lane * HS + col0 + j] = fmaxf(a0[j], 0.f);
        hl[(64 + lane) * HS + col0 + j] = fmaxf(a1[j], 0.f);
    }
    {
        const float4* __restrict__ s4 = (const float4*)W2;
        float4* __restrict__ d4 = (float4*)Wl;
        for (int i = tid; i < 1024; i += 256) d4[i] = s4[i];
    }
    __syncthreads();

    // ---- layer 2 ----
#pragma unroll
    for (int j = 0; j < 16; ++j) { a0[j] = b2[col0 + j]; a1[j] = a0[j]; }
    for (int c = 0; c < 16; ++c) {
        float h0 = hl[lane * HS + 4 * c + 0];
        float h1 = hl[lane * HS + 4 * c + 1];
        float h2 = hl[lane * HS + 4 * c + 2];
        float h3 = hl[lane * HS + 4 * c + 3];
        float g0 = hl[(64 + lane) * HS + 4 * c + 0];
        float g1 = hl[(64 + lane) * HS + 4 * c + 1];
        float g2 = hl[(64 + lane) * HS + 4 * c + 2];
        float g3 = hl[(64 + lane) * HS + 4 * c + 3];
        const float* __restrict__ w = Wl + c * 256 + col0;
#pragma unroll
        for (int j = 0; j < 16; ++j) {
            float wa = w[j], wb = w[64 + j], wc = w[128 + j], wd = w[192 + j];
            a0[j] = fmaf(h0, wa, a0[j]);
            a0[j] = fmaf(h1, wb, a0[j]);
            a0[j] = fmaf(h2, wc, a0[j]);
            a0[j] = fmaf(h3, wd, a0[j]);
            a1[j] = fmaf(g0, wa, a1[j]);
            a1[j] = fmaf(g1, wb, a1[j]);
            a1[j] = fmaf(g2, wc, a1[j]);
            a1[j] = fmaf(g3, wd, a1[j]);
        }
    }
    __syncthreads();
#pragma unroll
    for (int j = 0; j < 16; ++j) {
        hl[lane * HS + col0 + j] = fmaxf(a0[j], 0.f);
        hl[(64 + lane) * HS + col0 + j] = fmaxf(a1[j], 0.f);
    }
    if (act0) {
        float4* __restrict__ op = (float4*)(hout + (size_t)n0 * 64 + col0);
#pragma unroll
        for (int q = 0; q < 4; ++q)
            op[q] = make_float4(fmaxf(a0[q * 4], 0.f), fmaxf(a0[q * 4 + 1], 0.f),
                                fmaxf(a0[q * 4 + 2], 0.f), fmaxf(a0[q * 4 + 3], 0.f));
    }
    if (act1) {
        float4* __restrict__ op = (float4*)(hout + (size_t)n1 * 64 + col0);
#pragma unroll
        for (int q = 0; q < 4; ++q)
            op[q] = make_float4(fmaxf(a1[q * 4], 0.f), fmaxf(a1[q * 4 + 1], 0.f),
                                fmaxf(a1[q * 4 + 2], 0.f), fmaxf(a1[q * 4 + 3], 0.f));
    }
    {
        const float4* __restrict__ s4 = (const float4*)WfS;
        float4* __restrict__ d4 = (float4*)Wl;
        for (int i = tid; i < 1024; i += 256) d4[i] = s4[i];
    }
    __syncthreads();

    // ---- P0-F ----
#pragma unroll
    for (int j = 0; j < 16; ++j) { a0[j] = 0.f; a1[j] = 0.f; }
    for (int c = 0; c < 16; ++c) {
        float h0 = hl[lane * HS + 4 * c + 0];
        float h1 = hl[lane * HS + 4 * c + 1];
        float h2 = hl[lane * HS + 4 * c + 2];
        float h3 = hl[lane * HS + 4 * c + 3];
        float g0 = hl[(64 + lane) * HS + 4 * c + 0];
        float g1 = hl[(64 + lane) * HS + 4 * c + 1];
        float g2 = hl[(64 + lane) * HS + 4 * c + 2];
        float g3 = hl[(64 + lane) * HS + 4 * c + 3];
        const float* __restrict__ w = Wl + c * 256 + col0;
#pragma unroll
        for (int j = 0; j < 16; ++j) {
            float wa = w[j], wb = w[64 + j], wc = w[128 + j], wd = w[192 + j];
            a0[j] = fmaf(h0, wa, a0[j]);
            a0[j] = fmaf(h1, wb, a0[j]);
            a0[j] = fmaf(h2, wc, a0[j]);
            a0[j] = fmaf(h3, wd, a0[j]);
            a1[j] = fmaf(g0, wa, a1[j]);
            a1[j] = fmaf(g1, wb, a1[j]);
            a1[j] = fmaf(g2, wc, a1[j]);
            a1[j] = fmaf(g3, wd, a1[j]);
        }
    }
    __syncthreads();
    {
        const float4* __restrict__ s4 = (const float4*)WsS;
        float4* __restrict__ d4 = (float4*)Wl;
        for (int i = tid; i < 1024; i += 256) d4[i] = s4[i];
    }
    __syncthreads();

    // ---- P0-S + store ----
#pragma unroll
    for (int j = 0; j < 16; ++j) { s0[j] = 0.f; s1[j] = 0.f; }
    for (int c = 0; c < 16; ++c) {
        float h0 = hl[lane * HS + 4 * c + 0];
        float h1 = hl[lane * HS + 4 * c + 1];
        float h2 = hl[lane * HS + 4 * c + 2];
        float h3 = hl[lane * HS + 4 * c + 3];
        float g0 = hl[(64 + lane) * HS + 4 * c + 0];
        float g1 = hl[(64 + lane) * HS + 4 * c + 1];
        float g2 = hl[(64 + lane) * HS + 4 * c + 2];
        float g3 = hl[(64 + lane) * HS + 4 * c + 3];
        const float* __restrict__ w = Wl + c * 256 + col0;
#pragma unroll
        for (int j = 0; j < 16; ++j) {
            float wa = w[j], wb = w[64 + j], wc = w[128 + j], wd = w[192 + j];
            s0[j] = fmaf(h0, wa, s0[j]);
            s0[j] = fmaf(h1, wb, s0[j]);
            s0[j] = fmaf(h2, wc, s0[j]);
            s0[j] = fmaf(h3, wd, s0[j]);
            s1[j] = fmaf(g0, wa, s1[j]);
            s1[j] = fmaf(g1, wb, s1[j]);
            s1[j] = fmaf(g2, wc, s1[j]);
            s1[j] = fmaf(g3, wd, s1[j]);
        }
    }
    if (act0) {
        uint4* __restrict__ pp = (uint4*)(Pout + (size_t)n0 * 64 + col0);
#pragma unroll
        for (int q = 0; q < 4; ++q) {
            uint4 pk;
            pk.x = f2bf_rne(a0[q * 4])     | (f2bf_rne(s0[q * 4]) << 16);
            pk.y = f2bf_rne(a0[q * 4 + 1]) | (f2bf_rne(s0[q * 4 + 1]) << 16);
            pk.z = f2bf_rne(a0[q * 4 + 2]) | (f2bf_rne(s0[q * 4 + 2]) << 16);
            pk.w = f2bf_rne(a0[q * 4 + 3]) | (f2bf_rne(s0[q * 4 + 3]) << 16);
            pp[q] = pk;
        }
    }
    if (act1) {
        uint4* __restrict__ pp = (uint4*)(Pout + (size_t)n1 * 64 + col0);
#pragma unroll
        for (int q = 0; q < 4; ++q) {
            uint4 pk;
            pk.x = f2bf_rne(a1[q * 4])     | (f2bf_rne(s1[q * 4]) << 16);
            pk.y = f2bf_rne(a1[q * 4 + 1]) | (f2bf_rne(s1[q * 4 + 1]) << 16);
            pk.z = f2bf_rne(a1[q * 4 + 2]) | (f2bf_rne(s1[q * 4 + 2]) << 16);
            pk.w = f2bf_rne(a1[q * 4 + 3]) | (f2bf_rne(s1[q * 4 + 3]) << 16);
            pp[q] = pk;
        }
    }
    __syncthreads();
    {
        const float4* __restrict__ s4 = (const float4*)WfD;
        float4* __restrict__ d4 = (float4*)Wl;
        for (int i = tid; i < 1024; i += 256) d4[i] = s4[i];
    }
    __syncthreads();

    // ---- Q0-F ----
#pragma unroll
    for (int j = 0; j < 16; ++j) { a0[j] = bf[col0 + j]; a1[j] = a0[j]; }
    for (int c = 0; c < 16; ++c) {
        float h0 = hl[lane * HS + 4 * c + 0];
        float h1 = hl[lane * HS + 4 * c + 1];
        float h2 = hl[lane * HS + 4 * c + 2];
        float h3 = hl[lane * HS + 4 * c + 3];
        float g0 = hl[(64 + lane) * HS + 4 * c + 0];
        float g1 = hl[(64 + lane) * HS + 4 * c + 1];
        float g2 = hl[(64 + lane) * HS + 4 * c + 2];
        float g3 = hl[(64 + lane) * HS + 4 * c + 3];
        const float* __restrict__ w = Wl + c * 256 + col0;
#pragma unroll
        for (int j = 0; j < 16; ++j) {
            float wa = w[j], wb = w[64 + j], wc = w[128 + j], wd = w[192 + j];
            a0[j] = fmaf(h0, wa, a0[j]);
            a0[j] = fmaf(h1, wb, a0[j]);
            a0[j] = fmaf(h2, wc, a0[j]);
            a0[j] = fmaf(h3, wd, a0[j]);
            a1[j] = fmaf(g0, wa, a1[j]);
            a1[j] = fmaf(g1, wb, a1[j]);
            a1[j] = fmaf(g2, wc, a1[j]);
            a1[j] = fmaf(g3, wd, a1[j]);
        }
    }
    __syncthreads();
    {
        const float4* __restrict__ s4 = (const float4*)WsD;
        float4* __restrict__ d4 = (float4*)Wl;
        for (int i = tid; i < 1024; i += 256) d4[i] = s4[i];
    }
    __syncthreads();

    // ---- Q0-S + store ----
#pragma unroll
    for (int j = 0; j < 16; ++j) { s0[j] = bs[col0 + j]; s1[j] = s0[j]; }
    for (int c = 0; c < 16; ++c) {
        float h0 = hl[lane * HS + 4 * c + 0];
        float h1 = hl[lane * HS + 4 * c + 1];
        float h2 = hl[lane * HS + 4 * c + 2];
        float h3 = hl[lane * HS + 4 * c + 3];
        float g0 = hl[(64 + lane) * HS + 4 * c + 0];
        float g1 = hl[(64 + lane) * HS + 4 * c + 1];
        float g2 = hl[(64 + lane) * HS + 4 * c + 2];
        float g3 = hl[(64 + lane) * HS + 4 * c + 3];
        const float* __restrict__ w = Wl + c * 256 + col0;
#pragma unroll
        for (int j = 0; j < 16; ++j) {
            float wa = w[j], wb = w[64 + j], wc = w[128 + j], wd = w[192 + j];
            s0[j] = fmaf(h0, wa, s0[j]);
            s0[j] = fmaf(h1, wb, s0[j]);
            s0[j] = fmaf(h2, wc, s0[j]);
            s0[j] = fmaf(h3, wd, s0[j]);
            s1[j] = fmaf(g0, wa, s1[j]);
            s1[j] = fmaf(g1, wb, s1[j]);
            s1[j] = fmaf(g2, wc, s1[j]);
            s1[j] = fmaf(g3, wd, s1[j]);
        }
    }
    if (act0) {
        float4* __restrict__ qp = (float4*)(Qout + (size_t)n0 * 128 + col0 * 2);
#pragma unroll
        for (int q = 0; q < 8; ++q)
            qp[q] = make_float4(a0[q * 2], s0[q * 2], a0[q * 2 + 1], s0[q * 2 + 1]);
    }
    if (act1) {
        float4* __restrict__ qp = (float4*)(Qout + (size_t)n1 * 128 + col0 * 2);
#pragma unroll
        for (int q = 0; q < 8; ++q)
            qp[q] = make_float4(a1[q * 2], s1[q * 2], a1[q * 2 + 1], s1[q * 2 + 1]);
    }
}

// ---------------------------------------------------------------------------
// Gate projections: P (src half, packed bf16) and Q (dst half + bias, fp32).
// R20: SCALAR-PIPE h delivery. lane = output column, weights per-lane in
// VGPRs (dual-gate, 128 regs, launch_bounds(256,3) -> 170 cap), h rows are
// wave-uniform and the wave id is forced into an SGPR via readfirstlane so
// the compiler can promote h loads to s_load (separate pipe: zero LDS, no
// VMEM broadcast). K$-safe because h was written by a PREVIOUS kernel.
// 2 nodes in flight x 2 gates = 4 independent FMA chains. FMA order per
// output (k ascending, x..w) identical to R14/R19 -> bitwise-same.
// ---------------------------------------------------------------------------
__global__ __launch_bounds__(256, 3) void pjq_kernel(
    const float* __restrict__ h,
    const float* __restrict__ Wf, const float* __restrict__ Ws,
    const float* __restrict__ bfv, const float* __restrict__ bsv,
    unsigned int* __restrict__ P, float* __restrict__ Q, int N)
{
    const int lane = threadIdx.x & 63;
    // force wave id into SGPR so h addresses are provably wave-uniform
    const int wu = __builtin_amdgcn_readfirstlane((int)(threadIdx.x >> 6));
    const int base = (blockIdx.x * 4 + wu) * 32;   // 32 nodes per wave
    if (base >= N) return;
    const int nend = (base + 32 < N) ? base + 32 : N;

    // ---- P pass: rows 64..127, dual gate ----
    {
        float wf[64], ws[64];
#pragma unroll
        for (int k = 0; k < 64; ++k) {
            wf[k] = Wf[(64 + k) * 64 + lane];
            ws[k] = Ws[(64 + k) * 64 + lane];
        }
        for (int n = base; n < nend; n += 2) {
            const int m = (n + 1 < nend) ? n + 1 : n;
            const float4* __restrict__ h0 = (const float4*)(h + (size_t)n * 64);
            const float4* __restrict__ h1 = (const float4*)(h + (size_t)m * 64);
            float f0 = 0.f, s0 = 0.f, f1 = 0.f, s1 = 0.f;
#pragma unroll
            for (int c = 0; c < 16; ++c) {
                float4 v0 = h0[c];
                float4 v1 = h1[c];
                f0 = fmaf(v0.x, wf[4 * c + 0], f0);
                f0 = fmaf(v0.y, wf[4 * c + 1], f0);
                f0 = fmaf(v0.z, wf[4 * c + 2], f0);
                f0 = fmaf(v0.w, wf[4 * c + 3], f0);
                s0 = fmaf(v0.x, ws[4 * c + 0], s0);
                s0 = fmaf(v0.y, ws[4 * c + 1], s0);
                s0 = fmaf(v0.z, ws[4 * c + 2], s0);
                s0 = fmaf(v0.w, ws[4 * c + 3], s0);
                f1 = fmaf(v1.x, wf[4 * c + 0], f1);
                f1 = fmaf(v1.y, wf[4 * c + 1], f1);
                f1 = fmaf(v1.z, wf[4 * c + 2], f1);
                f1 = fmaf(v1.w, wf[4 * c + 3], f1);
                s1 = fmaf(v1.x, ws[4 * c + 0], s1);
                s1 = fmaf(v1.y, ws[4 * c + 1], s1);
                s1 = fmaf(v1.z, ws[4 * c + 2], s1);
                s1 = fmaf(v1.w, ws[4 * c + 3], s1);
            }
            P[(size_t)n * 64 + lane] = f2bf_rne(f0) | (f2bf_rne(s0) << 16);
            if (m > n)
                P[(size_t)m * 64 + lane] = f2bf_rne(f1) | (f2bf_rne(s1) << 16);
        }
    }

    // ---- Q pass: rows 0..63 + bias, dual gate ----
    {
        float wf[64], ws[64];
#pragma unroll
        for (int k = 0; k < 64; ++k) {
            wf[k] = Wf[k * 64 + lane];
            ws[k] = Ws[k * 64 + lane];
        }
        const float bfj = bfv[lane], bsj = bsv[lane];
        for (int n = base; n < nend; n += 2) {
            const int m = (n + 1 < nend) ? n + 1 : n;
            const float4* __restrict__ h0 = (const float4*)(h + (size_t)n * 64);
            const float4* __restrict__ h1 = (const float4*)(h + (size_t)m * 64);
            float f0 = bfj, s0 = bsj, f1 = bfj, s1 = bsj;
#pragma unroll
            for (int c = 0; c < 16; ++c) {
                float4 v0 = h0[c];
                float4 v1 = h1[c];
                f0 = fmaf(v0.x, wf[4 * c + 0], f0);
                f0 = fmaf(v0.y, wf[4 * c + 1], f0);
                f0 = fmaf(v0.z, wf[4 * c + 2], f0);
                f0 = fmaf(v0.w, wf[4 * c + 3], f0);
                s0 = fmaf(v0.x, ws[4 * c + 0], s0);
                s0 = fmaf(v0.y, ws[4 * c + 1], s0);
                s0 = fmaf(v0.z, ws[4 * c + 2], s0);
                s0 = fmaf(v0.w, ws[4 * c + 3], s0);
                f1 = fmaf(v1.x, wf[4 * c + 0], f1);
                f1 = fmaf(v1.y, wf[4 * c + 1], f1);
                f1 = fmaf(v1.z, wf[4 * c + 2], f1);
                f1 = fmaf(v1.w, wf[4 * c + 3], f1);
                s1 = fmaf(v1.x, ws[4 * c + 0], s1);
                s1 = fmaf(v1.y, ws[4 * c + 1], s1);
                s1 = fmaf(v1.z, ws[4 * c + 2], s1);
                s1 = fmaf(v1.w, ws[4 * c + 3], s1);
            }
            ((float2*)Q)[(size_t)n * 64 + lane] = make_float2(f0, s0);
            if (m > n)
                ((float2*)Q)[(size_t)m * 64 + lane] = make_float2(f1, s1);
        }
    }
}

// ---------------------------------------------------------------------------
// In-degree histogram (int)
// ---------------------------------------------------------------------------
__global__ __launch_bounds__(256) void deg_kernel(
    const int* __restrict__ dst, int* __restrict__ deg, int E)
{
    int e = blockIdx.x * blockDim.x + threadIdx.x;
    if (e < E) atomicAdd(&deg[dst[e]], 1);
}

// ---------------------------------------------------------------------------
// Three-phase exclusive scan over deg -> rowptr, cursor
// ---------------------------------------------------------------------------
__global__ __launch_bounds__(1024) void scanA_kernel(
    const int* __restrict__ deg, int* __restrict__ iscan,
    int* __restrict__ bsum, int N)
{
    __shared__ int lds[1024];
    int tid = threadIdx.x;
    int gid = blockIdx.x * 1024 + tid;
    int v = (gid < N) ? deg[gid] : 0;
    lds[tid] = v; __syncthreads();
    for (int off = 1; off < 1024; off <<= 1) {
        int t = (tid >= off) ? lds[tid - off] : 0;
        __syncthreads();
        lds[tid] += t;
        __syncthreads();
    }
    if (gid < N) iscan[gid] = lds[tid];
    if (tid == 1023) bsum[blockIdx.x] = lds[1023];
}

__global__ __launch_bounds__(128) void scanB_kernel(
    const int* __restrict__ bsum, int* __restrict__ boff, int nb)
{
    __shared__ int lds[128];
    int t = threadIdx.x;
    int v = (t < nb) ? bsum[t] : 0;
    lds[t] = v; __syncthreads();
    for (int off = 1; off < 128; off <<= 1) {
        int u = (t >= off) ? lds[t - off] : 0;
        __syncthreads();
        lds[t] += u;
        __syncthreads();
    }
    if (t < nb) boff[t] = lds[t] - v;  // exclusive
}

__global__ __launch_bounds__(256) void scanC_kernel(
    const int* __restrict__ iscan, const int* __restrict__ boff,
    const int* __restrict__ deg,
    int* __restrict__ rowptr, int* __restrict__ cursor, int N)
{
    int i = blockIdx.x * blockDim.x + threadIdx.x;
    if (i >= N) return;
    int incl = iscan[i] + boff[i >> 10];
    rowptr[i + 1] = incl;
    cursor[i] = incl - deg[i];
    if (i == 0) rowptr[0] = 0;
}

// ---------------------------------------------------------------------------
// Edge scatter into CSR order, packed (src, ea) int2
// ---------------------------------------------------------------------------
__global__ __launch_bounds__(256) void escatter_kernel(
    const int* __restrict__ src, const int* __restrict__ dst,
    const float* __restrict__ ea, int* __restrict__ cursor,
    int2* __restrict__ e_se, int E)
{
    int e = blockIdx.x * blockDim.x + threadIdx.x;
    if (e >= E) return;
    int pos = atomicAdd(&cursor[dst[e]], 1);
    e_se[pos] = make_int2(src[e], __float_as_int(ea[e]));
}

// ---------------------------------------------------------------------------
// CGConv edge pass. One wave per node, lane = dim. Q precomputed.
// At its memory-system floor (~130us/layer: 307MB of random 256B P-row
// gathers at ~2.4 TB/s effective -- confirmed by two independent structures
// (node-wave R14 and edge-parallel R18) landing within noise).
// ---------------------------------------------------------------------------
__global__ __launch_bounds__(256) void edge_kernel(
    const float* __restrict__ h, const int* __restrict__ rowptr,
    const int2* __restrict__ e_se,
    const unsigned int* __restrict__ P,
    const float* __restrict__ Q,
    const float* __restrict__ Wf, const float* __restrict__ Ws,
    float* __restrict__ hout)
{
    int n = blockIdx.x * 4 + (threadIdx.x >> 6);   // grid exactly covers GN
    int d = threadIdx.x & 63;

    const float2 qv = ((const float2*)Q)[(size_t)n * 64 + d];
    float qf = qv.x, qs = qv.y;
    float wf = Wf[128 * 64 + d];
    float ws = Ws[128 * 64 + d];

    size_t idx = (size_t)n * 64 + d;
    float hres = h[idx];

    int rb = rowptr[n], re = rowptr[n + 1];
    float agg = 0.f;
#pragma unroll 8
    for (int p = rb; p < re; ++p) {
        int2 se = e_se[p];         // wave-uniform 8B load
        int s = se.x;
        float ea = __int_as_float(se.y);
        unsigned int pv = P[(size_t)s * 64 + d];   // gathered dword (256B/wave)
        float pf = __uint_as_float(pv << 16);
        float psv = __uint_as_float(pv & 0xffff0000u);
        float xF = fmaf(ea, wf, qf + pf);
        float xS = fmaf(ea, ws, qs + psv);
        float sig = __builtin_amdgcn_rcpf(1.f + __expf(-xF));
        float t = __expf(-fabsf(xS));
        float sp = fmaxf(xS, 0.f) + __logf(1.f + t);
        agg = fmaf(sig, sp, agg);
    }

    float inv = 1.f / (float)max(re - rb, 1);
    hout[idx] = fmaxf(hres + agg * inv, 0.f);
}

// ---------------------------------------------------------------------------
// Graph segment starts: bm sorted; gstart[b] = first node of graph b.
// ---------------------------------------------------------------------------
__global__ __launch_bounds__(256) void gstart_kernel(
    const int* __restrict__ bm, int* __restrict__ gstart, int N)
{
    int i = blockIdx.x * blockDim.x + threadIdx.x;
    if (i >= N) return;
    int b = bm[i];
    int prev = (i == 0) ? -1 : bm[i - 1];
    for (int g = prev + 1; g <= b; ++g) gstart[g] = i;
    if (i == N - 1)
        for (int g = b + 1; g <= GB; ++g) gstart[g] = N;
}

// ---------------------------------------------------------------------------
// Segmented mean pool: one block per graph, no atomics.
// ---------------------------------------------------------------------------
__global__ __launch_bounds__(256) void pool_seg_kernel(
    const float* __restrict__ h, const int* __restrict__ gstart,
    float* __restrict__ g)
{
    int b = blockIdx.x;
    int s = gstart[b], e = gstart[b + 1];
    int d = threadIdx.x & 63;
    int w = threadIdx.x >> 6;
    float acc = 0.f;
    for (int n = s + w; n < e; n += 4)
        acc += h[(size_t)n * 64 + d];
    __shared__ float lds[256];
    lds[threadIdx.x] = acc;
    __syncthreads();
    if (w == 0) {
        acc = lds[d] + lds[64 + d] + lds[128 + d] + lds[192 + d];
        g[b * 64 + d] = acc / fmaxf((float)(e - s), 1.f);
    }
}

// ---------------------------------------------------------------------------
// Fused post-MLP (3 relu layers) + final dot + bias. One wave per graph.
// ---------------------------------------------------------------------------
__global__ __launch_bounds__(256) void postmlp_kernel(
    const float* __restrict__ g,
    const float* __restrict__ W0, const float* __restrict__ b0,
    const float* __restrict__ W1, const float* __restrict__ b1,
    const float* __restrict__ W2, const float* __restrict__ b2,
    const float* __restrict__ Wfin, const float* __restrict__ bfin,
    float* __restrict__ out)
{
    int b = blockIdx.x * 4 + (threadIdx.x >> 6);   // 32 blocks x 4 waves = 128
    int d = threadIdx.x & 63;
    float h = g[(size_t)b * 64 + d];

    float acc = b0[d];
#pragma unroll
    for (int k = 0; k < 64; ++k)
        acc = fmaf(__shfl(h, k, 64), W0[k * 64 + d], acc);
    h = fmaxf(acc, 0.f);

    acc = b1[d];
#pragma unroll
    for (int k = 0; k < 64; ++k)
        acc = fmaf(__shfl(h, k, 64), W1[k * 64 + d], acc);
    h = fmaxf(acc, 0.f);

    acc = b2[d];
#pragma unroll
    for (int k = 0; k < 64; ++k)
        acc = fmaf(__shfl(h, k, 64), W2[k * 64 + d], acc);
    h = fmaxf(acc, 0.f);

    float v = h * Wfin[d];
#pragma unroll
    for (int off = 32; off >= 1; off >>= 1)
        v += __shfl_xor(v, off, 64);
    if (d == 0) out[b] = v + bfin[0];
}

extern "C" void kernel_launch(void* const* d_in, const int* in_sizes, int n_in,
                              void* d_out, int out_size, void* d_ws, size_t ws_size,
                              hipStream_t stream)
{
    const float* X      = (const float*)d_in[0];
    const int*   eidx   = (const int*)d_in[1];
    const float* ea     = (const float*)d_in[3];
    const int*   bm     = (const int*)d_in[4];
    const float* pre_W0 = (const float*)d_in[5];
    const float* pre_b0 = (const float*)d_in[6];
    const float* pre_W1 = (const float*)d_in[7];
    const float* pre_b1 = (const float*)d_in[8];
    const float* pre_W2 = (const float*)d_in[9];
    const float* pre_b2 = (const float*)d_in[10];
    const float* cg_Wf  = (const float*)d_in[11];
    const float* cg_bf  = (const float*)d_in[12];
    const float* cg_Ws  = (const float*)d_in[13];
    const float* cg_bs  = (const float*)d_in[14];
    const float* post_W0 = (const float*)d_in[15];
    const float* post_b0 = (const float*)d_in[16];
    const float* post_W1 = (const float*)d_in[17];
    const float* post_b1 = (const float*)d_in[18];
    const float* post_W2 = (const float*)d_in[19];
    const float* post_b2 = (const float*)d_in[20];
    const float* post_Wf = (const float*)d_in[21];
    const float* post_bf = (const float*)d_in[22];

    const int* src = eidx;
    const int* dst = eidx + GE;

    // ---- workspace carve-up ----
    const size_t N64 = (size_t)GN * 64;
    float* hA    = (float*)d_ws;            // N*64
    float* hB    = hA + N64;                // N*64
    unsigned int* P = (unsigned int*)(hB + N64);  // N*64 packed bf16x2
    int* deg_i   = (int*)(P + N64);         // N
    int* iscan   = deg_i + GN;              // N
    int* bsum    = iscan + GN;              // 128
    int* boff    = bsum + 128;              // 128
    int* rowptr  = boff + 128;              // N+2 (padded so e_se is 8B-aligned)
    int* cursor  = rowptr + GN + 2;         // N
    int2* e_se   = (int2*)(cursor + GN);    // E int2 (8B-aligned)
    int* gstart  = (int*)(e_se + GE);       // B+1
    float* g0    = (float*)(gstart + GB + 1); // B*64 (8192 floats, keeps 8B align)
    float* Q     = g0 + (size_t)GB * 64;    // N*128 fp32 (qf,qs) pairs

    const int TPB = 256;
    int gridE  = (GE + TPB - 1) / TPB;
    int gridN  = (GN + TPB - 1) / TPB;         // 391 (lane=node grid)
    int gridP  = (GN + 127) / 128;             // 782 (dense grids: 128 nodes/block)
    int gridND = ((GN * 64) + TPB - 1) / TPB;  // 25000 (edge grid)
    int scanBlocks = (GN + 1023) / 1024;       // 98

    // per-layer weight pointers
    const float* Wf0 = cg_Wf;
    const float* Ws0 = cg_Ws;
    const float* Wf1 = cg_Wf + (size_t)1 * GZ * GD;
    const float* Ws1 = cg_Ws + (size_t)1 * GZ * GD;
    const float* Wf2 = cg_Wf + (size_t)2 * GZ * GD;
    const float* Ws2 = cg_Ws + (size_t)2 * GZ * GD;

    // fused pre-MLP (R14 col-split) + P0 + Q0
    premlp_kernel<<<gridP, TPB, 0, stream>>>(
        X, pre_W0, pre_b0, pre_W1, pre_b1, pre_W2, pre_b2,
        Wf0, Ws0, Wf0 + 64 * 64, Ws0 + 64 * 64, cg_bf, cg_bs,
        hA, P, Q, GN);

    // degree + CSR build
    hipMemsetAsync(deg_i, 0, GN * sizeof(int), stream);
    deg_kernel<<<gridE, TPB, 0, stream>>>(dst, deg_i, GE);
    scanA_kernel<<<scanBlocks, 1024, 0, stream>>>(deg_i, iscan, bsum, GN);
    scanB_kernel<<<1, 128, 0, stream>>>(bsum, boff, scanBlocks);
    scanC_kernel<<<gridN, TPB, 0, stream>>>(iscan, boff, deg_i, rowptr, cursor, GN);
    escatter_kernel<<<gridE, TPB, 0, stream>>>(src, dst, ea, cursor, e_se, GE);

    // graph segment starts (bm sorted)
    gstart_kernel<<<gridN, TPB, 0, stream>>>(bm, gstart, GN);

    // CGConv layers: node-wave edge pass + scalar-pipe P/Q projection
    edge_kernel<<<gridND, TPB, 0, stream>>>(
        hA, rowptr, e_se, P, Q, Wf0, Ws0, hB);
    pjq_kernel<<<gridP, TPB, 0, stream>>>(
        hB, Wf1, Ws1, cg_bf + GD, cg_bs + GD, P, Q, GN);
    edge_kernel<<<gridND, TPB, 0, stream>>>(
        hB, rowptr, e_se, P, Q, Wf1, Ws1, hA);
    pjq_kernel<<<gridP, TPB, 0, stream>>>(
        hA, Wf2, Ws2, cg_bf + 2 * GD, cg_bs + 2 * GD, P, Q, GN);
    edge_kernel<<<gridND, TPB, 0, stream>>>(
        hA, rowptr, e_se, P, Q, Wf2, Ws2, hB);

    // segmented mean pool (no atomics)
    pool_seg_kernel<<<GB, TPB, 0, stream>>>(hB, gstart, g0);

    // fused post-MLP + final projection
    postmlp_kernel<<<GB / 4, TPB, 0, stream>>>(
        g0, post_W0, post_b0, post_W1, post_b1, post_W2, post_b2,
        post_Wf, post_bf, (float*)d_out);
}

// Round 11
// 820.003 us; speedup vs baseline: 1.1243x; 1.1243x over previous
//
#include <hip/hip_runtime.h>
#include <hip/hip_bf16.h>
#include <math.h>

// Problem constants (fixed by the reference)
#define GN 100000   // nodes
#define GE 1200000  // edges
#define GB 128      // graphs
#define GF 92       // raw features
#define GD 64       // hidden dim
#define GL 3        // CGConv layers
#define GZ 129      // 2*D+1

#define HS 65       // padded LDS h-tile stride (bank = lane+off -> conflict-free)

// round-to-nearest-even fp32 -> bf16 (returned in low 16 bits)
__device__ __forceinline__ unsigned int f2bf_rne(float x)
{
    unsigned int u = __float_as_uint(x);
    u += 0x7fffu + ((u >> 16) & 1u);
    return u >> 16;
}

// ---------------------------------------------------------------------------
// Fused pre-MLP (3 layers) + P0 + Q0.
// R21: lane = node (64 nodes/block), wave = 16-col slice with col0 forced
// wave-uniform via readfirstlane -> weight addresses are provably uniform ->
// compiler streams them on the SCALAR pipe (s_load_dwordx16 from K$), the
// one delivery path with a verified in-session precedent (pre-R10 premlp).
// h chains through a per-block LDS tile read PER-LANE (4 ds_read_b32/c ~= 23
// LDS cyc vs 128 VALU cyc -> LDS pipe no longer the wall that pinned
// R12/R14/R19 at ~30% VALU). Rolled loops (no I$ thrash). F/S gate passes
// sequential (SGPR peak 64) but pack/store once. Per-output FMA order
// (c ascending, x..w) identical to R14 -> bitwise-same results.
// ---------------------------------------------------------------------------
__global__ __launch_bounds__(256, 4) void premlp_kernel(
    const float* __restrict__ X,
    const float* __restrict__ W0, const float* __restrict__ b0,
    const float* __restrict__ W1, const float* __restrict__ b1,
    const float* __restrict__ W2, const float* __restrict__ b2,
    const float* __restrict__ WfD, const float* __restrict__ WsD,   // rows 0..63
    const float* __restrict__ WfS, const float* __restrict__ WsS,   // rows 64..127
    const float* __restrict__ bf, const float* __restrict__ bs,
    float* __restrict__ hout, unsigned int* __restrict__ Pout,
    float* __restrict__ Qout, int N)
{
    __shared__ float hl[64 * HS];               // 16.6 KB h tile (64 nodes)
    const int tid = threadIdx.x;
    const int lane = tid & 63;
    const int col0 = __builtin_amdgcn_readfirstlane((tid >> 6) << 4);
    const int base = blockIdx.x * 64;
    const int n = base + lane;
    const int nn = (n < N) ? n : (N - 1);
    const bool act = (n < N);

    float acc[16], acc2[16];

    // ---- L0: X (K=92) @ W0 + b0, relu -> hl ----
#pragma unroll
    for (int j = 0; j < 16; ++j) acc[j] = b0[col0 + j];
    {
        const float4* __restrict__ xr = (const float4*)(X + (size_t)nn * GF);
        for (int c = 0; c < 23; ++c) {
            float4 v = xr[c];
            const float* __restrict__ w = W0 + (c * 4) * 64 + col0;   // uniform
#pragma unroll
            for (int j = 0; j < 16; ++j) {
                acc[j] = fmaf(v.x, w[j], acc[j]);
                acc[j] = fmaf(v.y, w[64 + j], acc[j]);
                acc[j] = fmaf(v.z, w[128 + j], acc[j]);
                acc[j] = fmaf(v.w, w[192 + j], acc[j]);
            }
        }
    }
#pragma unroll
    for (int j = 0; j < 16; ++j) hl[lane * HS + col0 + j] = fmaxf(acc[j], 0.f);
    __syncthreads();

    // ---- L1: hl @ W1 + b1 ----
#pragma unroll
    for (int j = 0; j < 16; ++j) acc[j] = b1[col0 + j];
    for (int c = 0; c < 16; ++c) {
        float v0 = hl[lane * HS + 4 * c + 0];
        float v1 = hl[lane * HS + 4 * c + 1];
        float v2 = hl[lane * HS + 4 * c + 2];
        float v3 = hl[lane * HS + 4 * c + 3];
        const float* __restrict__ w = W1 + (c * 4) * 64 + col0;
#pragma unroll
        for (int j = 0; j < 16; ++j) {
            acc[j] = fmaf(v0, w[j], acc[j]);
            acc[j] = fmaf(v1, w[64 + j], acc[j]);
            acc[j] = fmaf(v2, w[128 + j], acc[j]);
            acc[j] = fmaf(v3, w[192 + j], acc[j]);
        }
    }
    __syncthreads();    // all reads of L0-h done
#pragma unroll
    for (int j = 0; j < 16; ++j) hl[lane * HS + col0 + j] = fmaxf(acc[j], 0.f);
    __syncthreads();

    // ---- L2: hl @ W2 + b2 ----
#pragma unroll
    for (int j = 0; j < 16; ++j) acc[j] = b2[col0 + j];
    for (int c = 0; c < 16; ++c) {
        float v0 = hl[lane * HS + 4 * c + 0];
        float v1 = hl[lane * HS + 4 * c + 1];
        float v2 = hl[lane * HS + 4 * c + 2];
        float v3 = hl[lane * HS + 4 * c + 3];
        const float* __restrict__ w = W2 + (c * 4) * 64 + col0;
#pragma unroll
        for (int j = 0; j < 16; ++j) {
            acc[j] = fmaf(v0, w[j], acc[j]);
            acc[j] = fmaf(v1, w[64 + j], acc[j]);
            acc[j] = fmaf(v2, w[128 + j], acc[j]);
            acc[j] = fmaf(v3, w[192 + j], acc[j]);
        }
    }
    __syncthreads();    // all reads of L1-h done
#pragma unroll
    for (int j = 0; j < 16; ++j) hl[lane * HS + col0 + j] = fmaxf(acc[j], 0.f);
    if (act) {
        float4* __restrict__ op = (float4*)(hout + (size_t)n * 64 + col0);
#pragma unroll
        for (int q = 0; q < 4; ++q)
            op[q] = make_float4(fmaxf(acc[q * 4], 0.f), fmaxf(acc[q * 4 + 1], 0.f),
                                fmaxf(acc[q * 4 + 2], 0.f), fmaxf(acc[q * 4 + 3], 0.f));
    }
    __syncthreads();    // final h visible to all waves; hl read-only below

    // ---- P0: F pass, S pass, pack + store ----
#pragma unroll
    for (int j = 0; j < 16; ++j) acc[j] = 0.f;
    for (int c = 0; c < 16; ++c) {
        float v0 = hl[lane * HS + 4 * c + 0];
        float v1 = hl[lane * HS + 4 * c + 1];
        float v2 = hl[lane * HS + 4 * c + 2];
        float v3 = hl[lane * HS + 4 * c + 3];
        const float* __restrict__ w = WfS + (c * 4) * 64 + col0;
#pragma unroll
        for (int j = 0; j < 16; ++j) {
            acc[j] = fmaf(v0, w[j], acc[j]);
            acc[j] = fmaf(v1, w[64 + j], acc[j]);
            acc[j] = fmaf(v2, w[128 + j], acc[j]);
            acc[j] = fmaf(v3, w[192 + j], acc[j]);
        }
    }
#pragma unroll
    for (int j = 0; j < 16; ++j) acc2[j] = 0.f;
    for (int c = 0; c < 16; ++c) {
        float v0 = hl[lane * HS + 4 * c + 0];
        float v1 = hl[lane * HS + 4 * c + 1];
        float v2 = hl[lane * HS + 4 * c + 2];
        float v3 = hl[lane * HS + 4 * c + 3];
        const float* __restrict__ w = WsS + (c * 4) * 64 + col0;
#pragma unroll
        for (int j = 0; j < 16; ++j) {
            acc2[j] = fmaf(v0, w[j], acc2[j]);
            acc2[j] = fmaf(v1, w[64 + j], acc2[j]);
            acc2[j] = fmaf(v2, w[128 + j], acc2[j]);
            acc2[j] = fmaf(v3, w[192 + j], acc2[j]);
        }
    }
    if (act) {
        uint4* __restrict__ pp = (uint4*)(Pout + (size_t)n * 64 + col0);
#pragma unroll
        for (int q = 0; q < 4; ++q) {
            uint4 pk;
            pk.x = f2bf_rne(acc[q * 4])     | (f2bf_rne(acc2[q * 4]) << 16);
            pk.y = f2bf_rne(acc[q * 4 + 1]) | (f2bf_rne(acc2[q * 4 + 1]) << 16);
            pk.z = f2bf_rne(acc[q * 4 + 2]) | (f2bf_rne(acc2[q * 4 + 2]) << 16);
            pk.w = f2bf_rne(acc[q * 4 + 3]) | (f2bf_rne(acc2[q * 4 + 3]) << 16);
            pp[q] = pk;
        }
    }

    // ---- Q0: F pass, S pass, store fp32 (qf,qs) pairs ----
#pragma unroll
    for (int j = 0; j < 16; ++j) acc[j] = bf[col0 + j];
    for (int c = 0; c < 16; ++c) {
        float v0 = hl[lane * HS + 4 * c + 0];
        float v1 = hl[lane * HS + 4 * c + 1];
        float v2 = hl[lane * HS + 4 * c + 2];
        float v3 = hl[lane * HS + 4 * c + 3];
        const float* __restrict__ w = WfD + (c * 4) * 64 + col0;
#pragma unroll
        for (int j = 0; j < 16; ++j) {
            acc[j] = fmaf(v0, w[j], acc[j]);
            acc[j] = fmaf(v1, w[64 + j], acc[j]);
            acc[j] = fmaf(v2, w[128 + j], acc[j]);
            acc[j] = fmaf(v3, w[192 + j], acc[j]);
        }
    }
#pragma unroll
    for (int j = 0; j < 16; ++j) acc2[j] = bs[col0 + j];
    for (int c = 0; c < 16; ++c) {
        float v0 = hl[lane * HS + 4 * c + 0];
        float v1 = hl[lane * HS + 4 * c + 1];
        float v2 = hl[lane * HS + 4 * c + 2];
        float v3 = hl[lane * HS + 4 * c + 3];
        const float* __restrict__ w = WsD + (c * 4) * 64 + col0;
#pragma unroll
        for (int j = 0; j < 16; ++j) {
            acc2[j] = fmaf(v0, w[j], acc2[j]);
            acc2[j] = fmaf(v1, w[64 + j], acc2[j]);
            acc2[j] = fmaf(v2, w[128 + j], acc2[j]);
            acc2[j] = fmaf(v3, w[192 + j], acc2[j]);
        }
    }
    if (act) {
        float4* __restrict__ qp = (float4*)(Qout + (size_t)n * 128 + col0 * 2);
#pragma unroll
        for (int q = 0; q < 8; ++q)
            qp[q] = make_float4(acc[q * 2], acc2[q * 2], acc[q * 2 + 1], acc2[q * 2 + 1]);
    }
}

// ---------------------------------------------------------------------------
// Gate projections: P (src half, packed bf16) and Q (dst half + bias, fp32).
// R21: same scalar-pipe-weights structure as premlp. h staged coalesced
// into the LDS tile once, then 4 read-only passes.
// ---------------------------------------------------------------------------
__global__ __launch_bounds__(256, 4) void pjq_kernel(
    const float* __restrict__ h,
    const float* __restrict__ Wf, const float* __restrict__ Ws,
    const float* __restrict__ bfv, const float* __restrict__ bsv,
    unsigned int* __restrict__ P, float* __restrict__ Q, int N)
{
    __shared__ float hl[64 * HS];
    const int tid = threadIdx.x;
    const int lane = tid & 63;
    const int col0 = __builtin_amdgcn_readfirstlane((tid >> 6) << 4);
    const int base = blockIdx.x * 64;
    const int n = base + lane;
    const bool act = (n < N);

    // stage h tile (coalesced global read, padded LDS write)
    for (int q = tid; q < 1024; q += 256) {
        int r = q >> 4, c4 = q & 15;
        int rr = base + r; rr = (rr < N) ? rr : (N - 1);
        float4 v = ((const float4*)(h + (size_t)rr * 64))[c4];
        float* dp = hl + r * HS + c4 * 4;
        dp[0] = v.x; dp[1] = v.y; dp[2] = v.z; dp[3] = v.w;
    }
    __syncthreads();

    float acc[16], acc2[16];

    // ---- P: F pass (Wf rows 64..127), S pass (Ws rows 64..127) ----
#pragma unroll
    for (int j = 0; j < 16; ++j) acc[j] = 0.f;
    for (int c = 0; c < 16; ++c) {
        float v0 = hl[lane * HS + 4 * c + 0];
        float v1 = hl[lane * HS + 4 * c + 1];
        float v2 = hl[lane * HS + 4 * c + 2];
        float v3 = hl[lane * HS + 4 * c + 3];
        const float* __restrict__ w = Wf + (64 + c * 4) * 64 + col0;
#pragma unroll
        for (int j = 0; j < 16; ++j) {
            acc[j] = fmaf(v0, w[j], acc[j]);
            acc[j] = fmaf(v1, w[64 + j], acc[j]);
            acc[j] = fmaf(v2, w[128 + j], acc[j]);
            acc[j] = fmaf(v3, w[192 + j], acc[j]);
        }
    }
#pragma unroll
    for (int j = 0; j < 16; ++j) acc2[j] = 0.f;
    for (int c = 0; c < 16; ++c) {
        float v0 = hl[lane * HS + 4 * c + 0];
        float v1 = hl[lane * HS + 4 * c + 1];
        float v2 = hl[lane * HS + 4 * c + 2];
        float v3 = hl[lane * HS + 4 * c + 3];
        const float* __restrict__ w = Ws + (64 + c * 4) * 64 + col0;
#pragma unroll
        for (int j = 0; j < 16; ++j) {
            acc2[j] = fmaf(v0, w[j], acc2[j]);
            acc2[j] = fmaf(v1, w[64 + j], acc2[j]);
            acc2[j] = fmaf(v2, w[128 + j], acc2[j]);
            acc2[j] = fmaf(v3, w[192 + j], acc2[j]);
        }
    }
    if (act) {
        uint4* __restrict__ pp = (uint4*)(P + (size_t)n * 64 + col0);
#pragma unroll
        for (int q = 0; q < 4; ++q) {
            uint4 pk;
            pk.x = f2bf_rne(acc[q * 4])     | (f2bf_rne(acc2[q * 4]) << 16);
            pk.y = f2bf_rne(acc[q * 4 + 1]) | (f2bf_rne(acc2[q * 4 + 1]) << 16);
            pk.z = f2bf_rne(acc[q * 4 + 2]) | (f2bf_rne(acc2[q * 4 + 2]) << 16);
            pk.w = f2bf_rne(acc[q * 4 + 3]) | (f2bf_rne(acc2[q * 4 + 3]) << 16);
            pp[q] = pk;
        }
    }

    // ---- Q: F pass (Wf rows 0..63 + bf), S pass (Ws rows 0..63 + bs) ----
#pragma unroll
    for (int j = 0; j < 16; ++j) acc[j] = bfv[col0 + j];
    for (int c = 0; c < 16; ++c) {
        float v0 = hl[lane * HS + 4 * c + 0];
        float v1 = hl[lane * HS + 4 * c + 1];
        float v2 = hl[lane * HS + 4 * c + 2];
        float v3 = hl[lane * HS + 4 * c + 3];
        const float* __restrict__ w = Wf + (c * 4) * 64 + col0;
#pragma unroll
        for (int j = 0; j < 16; ++j) {
            acc[j] = fmaf(v0, w[j], acc[j]);
            acc[j] = fmaf(v1, w[64 + j], acc[j]);
            acc[j] = fmaf(v2, w[128 + j], acc[j]);
            acc[j] = fmaf(v3, w[192 + j], acc[j]);
        }
    }
#pragma unroll
    for (int j = 0; j < 16; ++j) acc2[j] = bsv[col0 + j];
    for (int c = 0; c < 16; ++c) {
        float v0 = hl[lane * HS + 4 * c + 0];
        float v1 = hl[lane * HS + 4 * c + 1];
        float v2 = hl[lane * HS + 4 * c + 2];
        float v3 = hl[lane * HS + 4 * c + 3];
        const float* __restrict__ w = Ws + (c * 4) * 64 + col0;
#pragma unroll
        for (int j = 0; j < 16; ++j) {
            acc2[j] = fmaf(v0, w[j], acc2[j]);
            acc2[j] = fmaf(v1, w[64 + j], acc2[j]);
            acc2[j] = fmaf(v2, w[128 + j], acc2[j]);
            acc2[j] = fmaf(v3, w[192 + j], acc2[j]);
        }
    }
    if (act) {
        float4* __restrict__ qp = (float4*)(Q + (size_t)n * 128 + col0 * 2);
#pragma unroll
        for (int q = 0; q < 8; ++q)
            qp[q] = make_float4(acc[q * 2], acc2[q * 2], acc[q * 2 + 1], acc2[q * 2 + 1]);
    }
}

// ---------------------------------------------------------------------------
// In-degree histogram (int)
// ---------------------------------------------------------------------------
__global__ __launch_bounds__(256) void deg_kernel(
    const int* __restrict__ dst, int* __restrict__ deg, int E)
{
    int e = blockIdx.x * blockDim.x + threadIdx.x;
    if (e < E) atomicAdd(&deg[dst[e]], 1);
}

// ---------------------------------------------------------------------------
// Three-phase exclusive scan over deg -> rowptr, cursor
// ---------------------------------------------------------------------------
__global__ __launch_bounds__(1024) void scanA_kernel(
    const int* __restrict__ deg, int* __restrict__ iscan,
    int* __restrict__ bsum, int N)
{
    __shared__ int lds[1024];
    int tid = threadIdx.x;
    int gid = blockIdx.x * 1024 + tid;
    int v = (gid < N) ? deg[gid] : 0;
    lds[tid] = v; __syncthreads();
    for (int off = 1; off < 1024; off <<= 1) {
        int t = (tid >= off) ? lds[tid - off] : 0;
        __syncthreads();
        lds[tid] += t;
        __syncthreads();
    }
    if (gid < N) iscan[gid] = lds[tid];
    if (tid == 1023) bsum[blockIdx.x] = lds[1023];
}

__global__ __launch_bounds__(128) void scanB_kernel(
    const int* __restrict__ bsum, int* __restrict__ boff, int nb)
{
    __shared__ int lds[128];
    int t = threadIdx.x;
    int v = (t < nb) ? bsum[t] : 0;
    lds[t] = v; __syncthreads();
    for (int off = 1; off < 128; off <<= 1) {
        int u = (t >= off) ? lds[t - off] : 0;
        __syncthreads();
        lds[t] += u;
        __syncthreads();
    }
    if (t < nb) boff[t] = lds[t] - v;  // exclusive
}

__global__ __launch_bounds__(256) void scanC_kernel(
    const int* __restrict__ iscan, const int* __restrict__ boff,
    const int* __restrict__ deg,
    int* __restrict__ rowptr, int* __restrict__ cursor, int N)
{
    int i = blockIdx.x * blockDim.x + threadIdx.x;
    if (i >= N) return;
    int incl = iscan[i] + boff[i >> 10];
    rowptr[i + 1] = incl;
    cursor[i] = incl - deg[i];
    if (i == 0) rowptr[0] = 0;
}

// ---------------------------------------------------------------------------
// Edge scatter into CSR order, packed (src, ea) int2
// ---------------------------------------------------------------------------
__global__ __launch_bounds__(256) void escatter_kernel(
    const int* __restrict__ src, const int* __restrict__ dst,
    const float* __restrict__ ea, int* __restrict__ cursor,
    int2* __restrict__ e_se, int E)
{
    int e = blockIdx.x * blockDim.x + threadIdx.x;
    if (e >= E) return;
    int pos = atomicAdd(&cursor[dst[e]], 1);
    e_se[pos] = make_int2(src[e], __float_as_int(ea[e]));
}

// ---------------------------------------------------------------------------
// CGConv edge pass. One wave per node, lane = dim. Q precomputed.
// At its memory-system floor (~130us/layer: 307MB of random 256B P-row
// gathers; confirmed by node-wave and edge-parallel structures landing
// within noise of each other).
// ---------------------------------------------------------------------------
__global__ __launch_bounds__(256) void edge_kernel(
    const float* __restrict__ h, const int* __restrict__ rowptr,
    const int2* __restrict__ e_se,
    const unsigned int* __restrict__ P,
    const float* __restrict__ Q,
    const float* __restrict__ Wf, const float* __restrict__ Ws,
    float* __restrict__ hout)
{
    int n = blockIdx.x * 4 + (threadIdx.x >> 6);   // grid exactly covers GN
    int d = threadIdx.x & 63;

    const float2 qv = ((const float2*)Q)[(size_t)n * 64 + d];
    float qf = qv.x, qs = qv.y;
    float wf = Wf[128 * 64 + d];
    float ws = Ws[128 * 64 + d];

    size_t idx = (size_t)n * 64 + d;
    float hres = h[idx];

    int rb = rowptr[n], re = rowptr[n + 1];
    float agg = 0.f;
#pragma unroll 8
    for (int p = rb; p < re; ++p) {
        int2 se = e_se[p];         // wave-uniform 8B load
        int s = se.x;
        float ea = __int_as_float(se.y);
        unsigned int pv = P[(size_t)s * 64 + d];   // gathered dword (256B/wave)
        float pf = __uint_as_float(pv << 16);
        float psv = __uint_as_float(pv & 0xffff0000u);
        float xF = fmaf(ea, wf, qf + pf);
        float xS = fmaf(ea, ws, qs + psv);
        float sig = __builtin_amdgcn_rcpf(1.f + __expf(-xF));
        float t = __expf(-fabsf(xS));
        float sp = fmaxf(xS, 0.f) + __logf(1.f + t);
        agg = fmaf(sig, sp, agg);
    }

    float inv = 1.f / (float)max(re - rb, 1);
    hout[idx] = fmaxf(hres + agg * inv, 0.f);
}

// ---------------------------------------------------------------------------
// Graph segment starts: bm sorted; gstart[b] = first node of graph b.
// ---------------------------------------------------------------------------
__global__ __launch_bounds__(256) void gstart_kernel(
    const int* __restrict__ bm, int* __restrict__ gstart, int N)
{
    int i = blockIdx.x * blockDim.x + threadIdx.x;
    if (i >= N) return;
    int b = bm[i];
    int prev = (i == 0) ? -1 : bm[i - 1];
    for (int g = prev + 1; g <= b; ++g) gstart[g] = i;
    if (i == N - 1)
        for (int g = b + 1; g <= GB; ++g) gstart[g] = N;
}

// ---------------------------------------------------------------------------
// Segmented mean pool: one block per graph, no atomics.
// ---------------------------------------------------------------------------
__global__ __launch_bounds__(256) void pool_seg_kernel(
    const float* __restrict__ h, const int* __restrict__ gstart,
    float* __restrict__ g)
{
    int b = blockIdx.x;
    int s = gstart[b], e = gstart[b + 1];
    int d = threadIdx.x & 63;
    int w = threadIdx.x >> 6;
    float acc = 0.f;
    for (int n = s + w; n < e; n += 4)
        acc += h[(size_t)n * 64 + d];
    __shared__ float lds[256];
    lds[threadIdx.x] = acc;
    __syncthreads();
    if (w == 0) {
        acc = lds[d] + lds[64 + d] + lds[128 + d] + lds[192 + d];
        g[b * 64 + d] = acc / fmaxf((float)(e - s), 1.f);
    }
}

// ---------------------------------------------------------------------------
// Fused post-MLP (3 relu layers) + final dot + bias. One wave per graph.
// ---------------------------------------------------------------------------
__global__ __launch_bounds__(256) void postmlp_kernel(
    const float* __restrict__ g,
    const float* __restrict__ W0, const float* __restrict__ b0,
    const float* __restrict__ W1, const float* __restrict__ b1,
    const float* __restrict__ W2, const float* __restrict__ b2,
    const float* __restrict__ Wfin, const float* __restrict__ bfin,
    float* __restrict__ out)
{
    int b = blockIdx.x * 4 + (threadIdx.x >> 6);   // 32 blocks x 4 waves = 128
    int d = threadIdx.x & 63;
    float h = g[(size_t)b * 64 + d];

    float acc = b0[d];
#pragma unroll
    for (int k = 0; k < 64; ++k)
        acc = fmaf(__shfl(h, k, 64), W0[k * 64 + d], acc);
    h = fmaxf(acc, 0.f);

    acc = b1[d];
#pragma unroll
    for (int k = 0; k < 64; ++k)
        acc = fmaf(__shfl(h, k, 64), W1[k * 64 + d], acc);
    h = fmaxf(acc, 0.f);

    acc = b2[d];
#pragma unroll
    for (int k = 0; k < 64; ++k)
        acc = fmaf(__shfl(h, k, 64), W2[k * 64 + d], acc);
    h = fmaxf(acc, 0.f);

    float v = h * Wfin[d];
#pragma unroll
    for (int off = 32; off >= 1; off >>= 1)
        v += __shfl_xor(v, off, 64);
    if (d == 0) out[b] = v + bfin[0];
}

extern "C" void kernel_launch(void* const* d_in, const int* in_sizes, int n_in,
                              void* d_out, int out_size, void* d_ws, size_t ws_size,
                              hipStream_t stream)
{
    const float* X      = (const float*)d_in[0];
    const int*   eidx   = (const int*)d_in[1];
    const float* ea     = (const float*)d_in[3];
    const int*   bm     = (const int*)d_in[4];
    const float* pre_W0 = (const float*)d_in[5];
    const float* pre_b0 = (const float*)d_in[6];
    const float* pre_W1 = (const float*)d_in[7];
    const float* pre_b1 = (const float*)d_in[8];
    const float* pre_W2 = (const float*)d_in[9];
    const float* pre_b2 = (const float*)d_in[10];
    const float* cg_Wf  = (const float*)d_in[11];
    const float* cg_bf  = (const float*)d_in[12];
    const float* cg_Ws  = (const float*)d_in[13];
    const float* cg_bs  = (const float*)d_in[14];
    const float* post_W0 = (const float*)d_in[15];
    const float* post_b0 = (const float*)d_in[16];
    const float* post_W1 = (const float*)d_in[17];
    const float* post_b1 = (const float*)d_in[18];
    const float* post_W2 = (const float*)d_in[19];
    const float* post_b2 = (const float*)d_in[20];
    const float* post_Wf = (const float*)d_in[21];
    const float* post_bf = (const float*)d_in[22];

    const int* src = eidx;
    const int* dst = eidx + GE;

    // ---- workspace carve-up ----
    const size_t N64 = (size_t)GN * 64;
    float* hA    = (float*)d_ws;            // N*64
    float* hB    = hA + N64;                // N*64
    unsigned int* P = (unsigned int*)(hB + N64);  // N*64 packed bf16x2
    int* deg_i   = (int*)(P + N64);         // N
    int* iscan   = deg_i + GN;              // N
    int* bsum    = iscan + GN;              // 128
    int* boff    = bsum + 128;              // 128
    int* rowptr  = boff + 128;              // N+2 (padded so e_se is 8B-aligned)
    int* cursor  = rowptr + GN + 2;         // N
    int2* e_se   = (int2*)(cursor + GN);    // E int2 (8B-aligned)
    int* gstart  = (int*)(e_se + GE);       // B+1
    float* g0    = (float*)(gstart + GB + 1); // B*64 (8192 floats, keeps 8B align)
    float* Q     = g0 + (size_t)GB * 64;    // N*128 fp32 (qf,qs) pairs

    const int TPB = 256;
    int gridE  = (GE + TPB - 1) / TPB;
    int gridN  = (GN + TPB - 1) / TPB;         // 391 (lane=node grid)
    int gridW  = (GN + 63) / 64;               // 1563 (64-node dense blocks)
    int gridND = ((GN * 64) + TPB - 1) / TPB;  // 25000 (edge grid)
    int scanBlocks = (GN + 1023) / 1024;       // 98

    // per-layer weight pointers
    const float* Wf0 = cg_Wf;
    const float* Ws0 = cg_Ws;
    const float* Wf1 = cg_Wf + (size_t)1 * GZ * GD;
    const float* Ws1 = cg_Ws + (size_t)1 * GZ * GD;
    const float* Wf2 = cg_Wf + (size_t)2 * GZ * GD;
    const float* Ws2 = cg_Ws + (size_t)2 * GZ * GD;

    // fused pre-MLP (scalar-pipe weights) + P0 + Q0
    premlp_kernel<<<gridW, TPB, 0, stream>>>(
        X, pre_W0, pre_b0, pre_W1, pre_b1, pre_W2, pre_b2,
        Wf0, Ws0, Wf0 + 64 * 64, Ws0 + 64 * 64, cg_bf, cg_bs,
        hA, P, Q, GN);

    // degree + CSR build
    hipMemsetAsync(deg_i, 0, GN * sizeof(int), stream);
    deg_kernel<<<gridE, TPB, 0, stream>>>(dst, deg_i, GE);
    scanA_kernel<<<scanBlocks, 1024, 0, stream>>>(deg_i, iscan, bsum, GN);
    scanB_kernel<<<1, 128, 0, stream>>>(bsum, boff, scanBlocks);
    scanC_kernel<<<gridN, TPB, 0, stream>>>(iscan, boff, deg_i, rowptr, cursor, GN);
    escatter_kernel<<<gridE, TPB, 0, stream>>>(src, dst, ea, cursor, e_se, GE);

    // graph segment starts (bm sorted)
    gstart_kernel<<<gridN, TPB, 0, stream>>>(bm, gstart, GN);

    // CGConv layers: node-wave edge pass + scalar-pipe P/Q projection
    edge_kernel<<<gridND, TPB, 0, stream>>>(
        hA, rowptr, e_se, P, Q, Wf0, Ws0, hB);
    pjq_kernel<<<gridW, TPB, 0, stream>>>(
        hB, Wf1, Ws1, cg_bf + GD, cg_bs + GD, P, Q, GN);
    edge_kernel<<<gridND, TPB, 0, stream>>>(
        hB, rowptr, e_se, P, Q, Wf1, Ws1, hA);
    pjq_kernel<<<gridW, TPB, 0, stream>>>(
        hA, Wf2, Ws2, cg_bf + 2 * GD, cg_bs + 2 * GD, P, Q, GN);
    edge_kernel<<<gridND, TPB, 0, stream>>>(
        hA, rowptr, e_se, P, Q, Wf2, Ws2, hB);

    // segmented mean pool (no atomics)
    pool_seg_kernel<<<GB, TPB, 0, stream>>>(hB, gstart, g0);

    // fused post-MLP + final projection
    postmlp_kernel<<<GB / 4, TPB, 0, stream>>>(
        g0, post_W0, post_b0, post_W1, post_b1, post_W2, post_b2,
        post_Wf, post_bf, (float*)d_out);
}